// Round 15
// baseline (1307.627 us; speedup 1.0000x reference)
//
#include <hip/hip_runtime.h>
#include <hip/hip_bf16.h>
#include <math.h>

// Problem constants
#define BB 64
#define NN 197
#define CC 768
#define HH 12
#define MLPD 3072
#define NKEEP 138
#define NKEEPA 97
#define NPATCH 196
#define NOUT_TOK 139
#define STILE 32

typedef __attribute__((ext_vector_type(8))) short bf16x8;
typedef __attribute__((ext_vector_type(4))) float f32x4;
typedef __attribute__((ext_vector_type(2))) float f32x2;

static __device__ inline ushort f2bf(float f) {
    __hip_bfloat16 h = __float2bfloat16(f);
    return *(ushort*)&h;
}
static __device__ inline float bf2f(ushort u) {
    __hip_bfloat16 h;
    *(ushort*)&h = u;
    return __bfloat162float(h);
}

// ---------------------------------------------------------------------------
// fp64 exp (poly), rel err ~1e-14; for softmax args (x <= 0, moderate)
// ---------------------------------------------------------------------------
__device__ inline double exp64(double x) {
    const double L2E    = 1.4426950408889634074;
    const double LN2_HI = 6.93147180369123816490e-01;
    const double LN2_LO = 1.90821492927058770002e-10;
    double nf = rint(x * L2E);
    double r  = fma(-nf, LN2_HI, x);
    r = fma(-nf, LN2_LO, r);
    double p = 1.0 / 3628800.0;
    p = fma(p, r, 1.0 / 362880.0);
    p = fma(p, r, 1.0 / 40320.0);
    p = fma(p, r, 1.0 / 5040.0);
    p = fma(p, r, 1.0 / 720.0);
    p = fma(p, r, 1.0 / 120.0);
    p = fma(p, r, 1.0 / 24.0);
    p = fma(p, r, 1.0 / 6.0);
    p = fma(p, r, 0.5);
    p = fma(p, r, 1.0);
    p = fma(p, r, 1.0);
    long long bits = ((long long)(1023 + (int)nf)) << 52;
    return p * __longlong_as_double(bits);
}

__device__ inline double wave_max64(double v) {
#pragma unroll
    for (int o = 32; o; o >>= 1) v = fmax(v, __shfl_xor(v, o));
    return v;
}
__device__ inline double wave_sum64(double v) {
#pragma unroll
    for (int o = 32; o; o >>= 1) v += __shfl_xor(v, o);
    return v;
}

// ---------------------------------------------------------------------------
// LayerNorm, fp64 wave-shuffle reductions; elements cached in registers.
// ---------------------------------------------------------------------------
__global__ __launch_bounds__(256) void ln_kernel(const float* __restrict__ in,
                                                 const float* __restrict__ g,
                                                 const float* __restrict__ b,
                                                 float* __restrict__ out32,
                                                 ushort* __restrict__ out16) {
    const int row = blockIdx.x;
    const int t = threadIdx.x;
    const int lane = t & 63, w = t >> 6;
    const float* xr = in + (size_t)row * CC;
    __shared__ double wred[4];

    const float v0 = xr[t], v1 = xr[t + 256], v2 = xr[t + 512];
    double s = (double)v0 + (double)v1 + (double)v2;
    s = wave_sum64(s);
    if (lane == 0) wred[w] = s;
    __syncthreads();
    const double mu = (wred[0] + wred[1] + wred[2] + wred[3]) * (1.0 / CC);

    const double d0 = (double)v0 - mu, d1 = (double)v1 - mu, d2 = (double)v2 - mu;
    double vs = d0 * d0 + d1 * d1 + d2 * d2;
    vs = wave_sum64(vs);
    __syncthreads();
    if (lane == 0) wred[w] = vs;
    __syncthreads();
    const double inv = 1.0 / sqrt((wred[0] + wred[1] + wred[2] + wred[3]) * (1.0 / CC) + 1e-5);

    const int cs[3] = {t, t + 256, t + 512};
    const double dv[3] = {d0, d1, d2};
#pragma unroll
    for (int i = 0; i < 3; i++) {
        float v = (float)(dv[i] * inv * (double)g[cs[i]] + (double)b[cs[i]]);
        if (out32) out32[(size_t)row * CC + cs[i]] = v;
        if (out16) out16[(size_t)row * CC + cs[i]] = f2bf(v);
    }
}

// ---------------------------------------------------------------------------
// Exact-path fp32 GEMM, fp64 merge every 16 k (bit-identical partial-sum
// boundaries to the validated version).
// BM=128, BN=128, BK=16, 256 threads, 8x8 microtile (halves LDS bytes/FMA).
// Fragment-pitched LDS (8-float fragments at 12-float pitch): fragment f
// starts at quad 3f mod 8 -> only f/f+8 alias = 2-way bank access (free).
// ---------------------------------------------------------------------------
__global__ __launch_bounds__(256) void gemm_qk_kernel(const float* __restrict__ A,
                                                      const float* __restrict__ Bw,
                                                      const float* __restrict__ bias,
                                                      float* __restrict__ C,
                                                      int K, int ldb, int ldc) {
    __shared__ float As[16][192];   // [k][frag*12 + e], frag<16, e<8
    __shared__ float Bs[16][192];
    const int tid = threadIdx.x;
    const int tx = tid & 15;        // B fragment (cols tx*8..+8)
    const int ty = tid >> 4;        // A fragment (rows ty*8..+8)
    const int m0 = blockIdx.y * 128;
    const int n0 = blockIdx.x * 128;

    const int a_k = tid & 15, a_g = tid >> 4;          // A loader: k, fragment
    const int b_c = tid & 127, b_kg = tid >> 7;        // B loader: col, k-half
    const int b_off = (b_c >> 3) * 12 + (b_c & 7);     // fragment-pitched col

    f32x2 acc2[8][4];
    double dacc[8][8];
#pragma unroll
    for (int i = 0; i < 8; i++) {
#pragma unroll
        for (int j = 0; j < 4; j++) acc2[i][j] = (f32x2){0.f, 0.f};
#pragma unroll
        for (int j = 0; j < 8; j++) dacc[i][j] = 0.0;
    }

    float a_reg[8], b_reg[8];
#pragma unroll
    for (int i = 0; i < 8; i++)
        a_reg[i] = A[(size_t)(m0 + a_g * 8 + i) * 768 + a_k];
#pragma unroll
    for (int i = 0; i < 8; i++)
        b_reg[i] = Bw[(size_t)(b_kg * 8 + i) * ldb + n0 + b_c];

    for (int k0 = 0; k0 < K; k0 += 16) {
        __syncthreads();
        *(float4*)&As[a_k][a_g * 12]     = make_float4(a_reg[0], a_reg[1], a_reg[2], a_reg[3]);
        *(float4*)&As[a_k][a_g * 12 + 4] = make_float4(a_reg[4], a_reg[5], a_reg[6], a_reg[7]);
#pragma unroll
        for (int i = 0; i < 8; i++) Bs[b_kg * 8 + i][b_off] = b_reg[i];
        __syncthreads();
        if (k0 + 16 < K) {
#pragma unroll
            for (int i = 0; i < 8; i++)
                a_reg[i] = A[(size_t)(m0 + a_g * 8 + i) * 768 + k0 + 16 + a_k];
#pragma unroll
            for (int i = 0; i < 8; i++)
                b_reg[i] = Bw[(size_t)(k0 + 16 + b_kg * 8 + i) * ldb + n0 + b_c];
        }
#pragma unroll
        for (int k = 0; k < 16; k++) {
            float4 a0 = *(const float4*)&As[k][ty * 12];
            float4 a1 = *(const float4*)&As[k][ty * 12 + 4];
            float4 bv0 = *(const float4*)&Bs[k][tx * 12];
            float4 bv1 = *(const float4*)&Bs[k][tx * 12 + 4];
            float a_[8] = {a0.x, a0.y, a0.z, a0.w, a1.x, a1.y, a1.z, a1.w};
            f32x2 b2[4] = {(f32x2){bv0.x, bv0.y}, (f32x2){bv0.z, bv0.w},
                           (f32x2){bv1.x, bv1.y}, (f32x2){bv1.z, bv1.w}};
#pragma unroll
            for (int i = 0; i < 8; i++) {
                f32x2 as = {a_[i], a_[i]};
#pragma unroll
                for (int j = 0; j < 4; j++)
                    acc2[i][j] = __builtin_elementwise_fma(as, b2[j], acc2[i][j]);
            }
        }
        // fp64 merge every 16 k (same cadence & order as validated kernel)
#pragma unroll
        for (int i = 0; i < 8; i++)
#pragma unroll
            for (int j = 0; j < 4; j++) {
                dacc[i][j * 2]     += (double)acc2[i][j][0];
                dacc[i][j * 2 + 1] += (double)acc2[i][j][1];
                acc2[i][j] = (f32x2){0.f, 0.f};
            }
    }

#pragma unroll
    for (int i = 0; i < 8; i++) {
        const int row = m0 + ty * 8 + i;
#pragma unroll
        for (int j = 0; j < 8; j++) {
            const int col = n0 + tx * 8 + j;
            C[(size_t)row * ldc + col] = (float)(dacc[i][j] + (double)bias[col]);
        }
    }
}

// ---------------------------------------------------------------------------
// bf16 MFMA GEMM: C[M,Nc] = A[M,K](bf16) @ Bt[Nc,K](bf16)^T + bias (+res/gelu)
// BM=128, BN=128, BK=32; 512 threads = 8 waves (2x4); wave tile 64x32.
// ---------------------------------------------------------------------------
template <int MODE, bool OUT_BF16>
__global__ __launch_bounds__(512) void mfma_gemm(const ushort* __restrict__ A,
                                                 const ushort* __restrict__ Bt,
                                                 const float* __restrict__ bias,
                                                 const float* __restrict__ res,
                                                 void* __restrict__ Cout,
                                                 int M, int K, int Nc) {
    __shared__ ushort As[128][40];
    __shared__ ushort Bs[128][40];
    const int tid = threadIdx.x;
    const int w = tid >> 6, lane = tid & 63;
    const int m0 = blockIdx.y * 128, n0 = blockIdx.x * 128;
    const int wr = w >> 2, wc = w & 3;
    const int sr = tid >> 2, sk = (tid & 3) * 8;
    const int lr = lane & 15, lq = lane >> 4;
    const int kq = lq * 8;

    f32x4 acc[4][2];
#pragma unroll
    for (int i = 0; i < 4; i++)
#pragma unroll
        for (int j = 0; j < 2; j++) acc[i][j] = (f32x4){0.f, 0.f, 0.f, 0.f};

    bf16x8 a_pre = *(const bf16x8*)&A[(size_t)(m0 + sr) * K + sk];
    bf16x8 b_pre = *(const bf16x8*)&Bt[(size_t)(n0 + sr) * K + sk];

    for (int k0 = 0; k0 < K; k0 += 32) {
        __syncthreads();
        *(bf16x8*)&As[sr][sk] = a_pre;
        *(bf16x8*)&Bs[sr][sk] = b_pre;
        __syncthreads();
        if (k0 + 32 < K) {
            a_pre = *(const bf16x8*)&A[(size_t)(m0 + sr) * K + k0 + 32 + sk];
            b_pre = *(const bf16x8*)&Bt[(size_t)(n0 + sr) * K + k0 + 32 + sk];
        }

        bf16x8 af[4], bfr[2];
#pragma unroll
        for (int i = 0; i < 4; i++) af[i] = *(const bf16x8*)&As[wr * 64 + i * 16 + lr][kq];
#pragma unroll
        for (int j = 0; j < 2; j++) bfr[j] = *(const bf16x8*)&Bs[wc * 32 + j * 16 + lr][kq];
#pragma unroll
        for (int i = 0; i < 4; i++)
#pragma unroll
            for (int j = 0; j < 2; j++)
                acc[i][j] = __builtin_amdgcn_mfma_f32_16x16x32_bf16(af[i], bfr[j], acc[i][j], 0, 0, 0);
    }

#pragma unroll
    for (int i = 0; i < 4; i++)
#pragma unroll
        for (int j = 0; j < 2; j++)
#pragma unroll
            for (int r = 0; r < 4; r++) {
                const int row = m0 + wr * 64 + i * 16 + lq * 4 + r;
                if (row >= M) continue;
                const int col = n0 + wc * 32 + j * 16 + lr;
                float v = acc[i][j][r] + bias[col];
                if (MODE == 1) v += res[(size_t)row * Nc + col];
                if (MODE == 2) v = 0.5f * v * (1.0f + erff(v * 0.70710678118654752f));
                if (OUT_BF16) ((ushort*)Cout)[(size_t)row * Nc + col] = f2bf(v);
                else ((float*)Cout)[(size_t)row * Nc + col] = v;
            }
}

// ---------------------------------------------------------------------------
// Weight transpose + bf16 convert: Wt[n][k] = bf16(W[k*ldw + n])
// ---------------------------------------------------------------------------
__global__ __launch_bounds__(256) void transw_kernel(const float* __restrict__ W, int ldw,
                                                     ushort* __restrict__ Wt, int K) {
    __shared__ float tile[32][33];
    const int n0 = blockIdx.x * 32, k0 = blockIdx.y * 32;
    const int tx = threadIdx.x & 31, ty = threadIdx.x >> 5;
#pragma unroll
    for (int r = 0; r < 32; r += 8)
        tile[ty + r][tx] = W[(size_t)(k0 + ty + r) * ldw + n0 + tx];
    __syncthreads();
#pragma unroll
    for (int r = 0; r < 32; r += 8)
        Wt[(size_t)(n0 + ty + r) * K + k0 + tx] = f2bf(tile[tx][ty + r]);
}

// ---------------------------------------------------------------------------
// V transpose to [b][h][d][224] bf16 (pads m in [197,224) zeroed).
// ---------------------------------------------------------------------------
__global__ __launch_bounds__(256) void transv_kernel(const ushort* __restrict__ vbf,
                                                     ushort* __restrict__ vbfT) {
    __shared__ ushort tile[32][72];
    const int mt = blockIdx.x, hh = blockIdx.y, b = blockIdx.z;
    const int t = threadIdx.x;
    {
        const int mm = t >> 3, dq = (t & 7) * 8;
        const int m = mt * 32 + mm;
        bf16x8 v = (bf16x8){0, 0, 0, 0, 0, 0, 0, 0};
        if (m < NN)
            v = *(const bf16x8*)&vbf[((size_t)(b * NN + m)) * CC + hh * 64 + dq];
        *(bf16x8*)&tile[mm][dq] = v;
    }
    __syncthreads();
    {
        const int d = t >> 2, mq = (t & 3) * 8;
        ushort tmp[8];
#pragma unroll
        for (int j = 0; j < 8; j++) tmp[j] = tile[mq + j][d];
        *(bf16x8*)&vbfT[(((size_t)(b * HH + hh)) * 64 + d) * 224 + mt * 32 + mq] =
            *(bf16x8*)tmp;
    }
}

// ---------------------------------------------------------------------------
// Fused attention: exact scores (fp32 fma + chunk-8 fp64) + fp64 softmax +
// MFMA PV. grid (7 tiles of 32 rows, B), 512 threads (8 waves).
// NOTE: scores merge MUST stay chunk-8 — chunk-16 spills fp64 accumulators
// to scratch (round 9: 14.8 GB HBM traffic, 25x slowdown).
// ---------------------------------------------------------------------------
#define KSTR 68
#define PSTR 232
__global__ __launch_bounds__(512) void attn_kernel(const float* __restrict__ qk,
                                                   const ushort* __restrict__ vbfT,
                                                   const float* __restrict__ amask,
                                                   ushort* __restrict__ xatt_bf,
                                                   double* __restrict__ cls64,
                                                   double* __restrict__ patch64) {
    const int tile = blockIdx.x;
    const int b = blockIdx.y;
    const int row0 = tile * STILE;
    const int nrows = min(STILE, NN - row0);
    const int t = threadIdx.x;
    const int w = t >> 6, lane = t & 63;

    __shared__ __align__(16) char pool[61776];
    float*  Kf = (float*)pool;               // [197][68]
    float*  Qf = (float*)(pool + 53584);     // [32][64]
    ushort* Vt = (ushort*)pool;              // [64][232]
    ushort* Pb = (ushort*)(pool + 32768);    // [32][232]

    int mcol[4], mc[4];
    bool mok[4];
#pragma unroll
    for (int c = 0; c < 4; c++) {
        mcol[c] = lane + 64 * c;
        mok[c] = mcol[c] < NN;
        mc[c] = mok[c] ? mcol[c] : 0;
    }
    int rloc[4];
    bool rok[4];
#pragma unroll
    for (int rr = 0; rr < 4; rr++) {
        rloc[rr] = w + 8 * rr;
        rok[rr] = rloc[rr] < nrows;
    }

    float mv[4][4];
#pragma unroll
    for (int rr = 0; rr < 4; rr++)
#pragma unroll
        for (int c = 0; c < 4; c++)
            mv[rr][c] = (rok[rr] && mok[c])
                ? amask[((size_t)(b * NN + row0 + rloc[rr])) * NN + mcol[c]] : 0.f;

    const int rt = w >> 2, ct = w & 3;
    const int lr = lane & 15, lq = lane >> 4;

    double hacc[4][4] = {};

    for (int h = 0; h < HH; ++h) {
        __syncthreads();
        for (int idx = t; idx < NN * 16; idx += 512) {
            int m = idx >> 4, dq = (idx & 15) * 4;
            *(float4*)&Kf[m * KSTR + dq] =
                *(const float4*)&qk[((size_t)(b * NN + m)) * 1536 + 768 + h * 64 + dq];
        }
        for (int idx = t; idx < nrows * 64; idx += 512) {
            int r = idx >> 6, d = idx & 63;
            Qf[r * 64 + d] = qk[((size_t)(b * NN + row0 + r)) * 1536 + h * 64 + d];
        }
        __syncthreads();

        double s[4][4] = {};
        {
            float facc[4][4] = {};
            for (int d0 = 0; d0 < 64; d0 += 4) {
                float4 qv[4];
#pragma unroll
                for (int rr = 0; rr < 4; rr++)
                    qv[rr] = rok[rr] ? *(const float4*)&Qf[rloc[rr] * 64 + d0]
                                     : make_float4(0.f, 0.f, 0.f, 0.f);
#pragma unroll
                for (int c = 0; c < 4; c++) {
                    float4 kv = *(const float4*)&Kf[mc[c] * KSTR + d0];
#pragma unroll
                    for (int rr = 0; rr < 4; rr++) {
                        facc[rr][c] = fmaf(qv[rr].x, kv.x,
                                      fmaf(qv[rr].y, kv.y,
                                      fmaf(qv[rr].z, kv.z,
                                      fmaf(qv[rr].w, kv.w, facc[rr][c]))));
                    }
                }
                if ((d0 & 4) == 4) {   // chunk-8 fp64 merge (do not widen!)
#pragma unroll
                    for (int rr = 0; rr < 4; rr++)
#pragma unroll
                        for (int c = 0; c < 4; c++) {
                            s[rr][c] += (double)facc[rr][c];
                            facc[rr][c] = 0.f;
                        }
                }
            }
        }
        __syncthreads();

#pragma unroll
        for (int rr = 0; rr < 4; rr++) {
            if (!rok[rr]) continue;  // wave-uniform
            double sc[4];
#pragma unroll
            for (int c = 0; c < 4; c++)
                sc[c] = mok[c] ? s[rr][c] * 0.125 : -1.0e300;
            double mx = fmax(fmax(sc[0], sc[1]), fmax(sc[2], sc[3]));
            mx = wave_max64(mx);
            double e[4];
#pragma unroll
            for (int c = 0; c < 4; c++)
                e[c] = mok[c] ? exp64(sc[c] - mx) * (double)mv[rr][c] : 0.0;
            double S = wave_sum64(e[0] + e[1] + e[2] + e[3]);
            double inv = 1.0 / (S + 1e-6);
            const double epsn = 1e-6 / 197.0;
#pragma unroll
            for (int c = 0; c < 4; c++) {
                if (!mok[c]) continue;
                double pr = (e[c] + epsn) * inv;
                Pb[rloc[rr] * PSTR + mcol[c]] = f2bf((float)pr);
                hacc[rr][c] += pr;
            }
        }
        // zero P pads (Pb aliases Kf region -> rewritten every head)
        for (int idx = t; idx < 32 * 27; idx += 512) {
            int r = idx / 27, m = 197 + idx % 27;
            Pb[r * PSTR + m] = 0;
        }
        for (int idx = t; idx < (STILE - nrows) * 197; idx += 512) {
            int r = nrows + idx / 197, m = idx % 197;
            Pb[r * PSTR + m] = 0;
        }
        // stage V from pre-transposed global: contiguous bf16x8, no conflicts
        {
            const ushort* vsrc = vbfT + ((size_t)(b * HH + h)) * 64 * 224;
            for (int idx = t; idx < 64 * 28; idx += 512) {
                int d = idx / 28, mb = (idx % 28) * 8;
                *(bf16x8*)&Vt[d * PSTR + mb] = *(const bf16x8*)&vsrc[d * 224 + mb];
            }
        }
        __syncthreads();

        f32x4 acc = (f32x4){0.f, 0.f, 0.f, 0.f};
#pragma unroll
        for (int k0 = 0; k0 < 224; k0 += 32) {
            bf16x8 pa = *(const bf16x8*)&Pb[(rt * 16 + lr) * PSTR + k0 + lq * 8];
            bf16x8 vb = *(const bf16x8*)&Vt[(ct * 16 + lr) * PSTR + k0 + lq * 8];
            acc = __builtin_amdgcn_mfma_f32_16x16x32_bf16(pa, vb, acc, 0, 0, 0);
        }
#pragma unroll
        for (int rg = 0; rg < 4; rg++) {
            const int row = rt * 16 + lq * 4 + rg;
            if (row < nrows)
                xatt_bf[((size_t)(b * NN + row0 + row)) * CC + h * 64 + ct * 16 + lr] =
                    f2bf(acc[rg]);
        }
    }

#pragma unroll
    for (int rr = 0; rr < 4; rr++) {
        if (!rok[rr]) continue;
        const int grow = row0 + rloc[rr];
#pragma unroll
        for (int c = 0; c < 4; c++) {
            if (!mok[c] || mcol[c] < 1) continue;
            double v = hacc[rr][c] * (1.0 / 12.0);
            if (grow == 0)
                cls64[(size_t)b * NPATCH + mcol[c] - 1] = v;
            else
                patch64[((size_t)b * NPATCH + grow - 1) * NPATCH + (mcol[c] - 1)] = v;
        }
    }
}

// ---------------------------------------------------------------------------
// Top-k (stable, descending) of cls64 + fp32 cls output.
// ---------------------------------------------------------------------------
__global__ __launch_bounds__(256) void topk_kernel(const double* __restrict__ cls,
                                                   int* __restrict__ tok,
                                                   float* __restrict__ tok_f,
                                                   float* __restrict__ out_cls) {
    const int b = blockIdx.x;
    const int t = threadIdx.x;
    __shared__ double v[NPATCH];
    if (t < NPATCH) {
        v[t] = cls[(size_t)b * NPATCH + t];
        out_cls[(size_t)b * NPATCH + t] = (float)v[t];
    }
    __syncthreads();
    if (t < NPATCH) {
        const double mvv = v[t];
        int cnt = 0;
        for (int i = 0; i < NPATCH; ++i) {
            double vi = v[i];
            cnt += (vi > mvv) || (vi == mvv && i < t);
        }
        if (cnt < NKEEP) {
            tok[b * NKEEP + cnt] = t;
            tok_f[b * NKEEP + cnt] = (float)t;
        }
    }
}

// gather x rows (fp32 residual base) and xatt rows (bf16 proj input)
__global__ __launch_bounds__(256) void gather_kernel(const float* __restrict__ x,
                                                     const ushort* __restrict__ xatt_bf,
                                                     const int* __restrict__ tok,
                                                     float* __restrict__ xp,
                                                     ushort* __restrict__ xattp) {
    const int i = blockIdx.x;
    const int b = blockIdx.y;
    const int t = threadIdx.x;
    const int src = (i == 0) ? 0 : (1 + tok[b * NKEEP + i - 1]);
    const float* sx = x + ((size_t)b * NN + src) * CC;
    float* dx = xp + ((size_t)b * NOUT_TOK + i) * CC;
    const ushort* sa = xatt_bf + ((size_t)b * NN + src) * CC;
    ushort* da = xattp + ((size_t)b * NOUT_TOK + i) * CC;
    if (t < 192) {
        ((float4*)dx)[t] = ((const float4*)sx)[t];
        ((uint2*)da)[t] = ((const uint2*)sa)[t];
    }
}

// mask from patch64 gathered on the fly
__global__ __launch_bounds__(256) void mask_kernel(const double* __restrict__ patch,
                                                   const int* __restrict__ tok,
                                                   float* __restrict__ omask) {
    const int i = blockIdx.x;
    const int b = blockIdx.y;
    const int t = threadIdx.x;
    float* orow = omask + ((size_t)b * NOUT_TOK + i) * NOUT_TOK;
    if (i == 0) {
        if (t < NOUT_TOK) orow[t] = 1.f;
        return;
    }
    __shared__ int tj[NKEEP];
    __shared__ double pr[NKEEP];
    if (t < NKEEP) tj[t] = tok[b * NKEEP + t];
    __syncthreads();
    const int ti = tj[i - 1];
    if (t < NKEEP) pr[t] = patch[((size_t)b * NPATCH + ti) * NPATCH + tj[t]];
    __syncthreads();
    if (t == 255) orow[0] = 1.f;
    if (t < NKEEP) {
        const double val = pr[t];
        int cnt = 0;
        for (int l = 0; l < NKEEP; ++l) cnt += (pr[l] > val);
        orow[1 + t] = (cnt < NKEEPA) ? 1.f : 0.f;
    }
}

// ---------------------------------------------------------------------------
extern "C" void kernel_launch(void* const* d_in, const int* in_sizes, int n_in,
                              void* d_out, int out_size, void* d_ws, size_t ws_size,
                              hipStream_t stream) {
    const float* x      = (const float*)d_in[0];
    const float* amask  = (const float*)d_in[1];
    const float* n1g    = (const float*)d_in[2];
    const float* n1b    = (const float*)d_in[3];
    const float* qkv_w  = (const float*)d_in[4];
    const float* qkv_b  = (const float*)d_in[5];
    const float* proj_w = (const float*)d_in[6];
    const float* proj_b = (const float*)d_in[7];
    const float* n2g    = (const float*)d_in[8];
    const float* n2b    = (const float*)d_in[9];
    const float* fc1_w  = (const float*)d_in[10];
    const float* fc1_b  = (const float*)d_in[11];
    const float* fc2_w  = (const float*)d_in[12];
    const float* fc2_b  = (const float*)d_in[13];

    float* ws = (float*)d_ws;
    // Workspace layout (float offsets). Total 49,114,240 f = 196.5 MB.
    const size_t A_OFF = 0;
    const size_t C_OFF = 9682944;
    const size_t B_OFF = 14524416;
    const size_t D_OFF = 33890304;
    const size_t E_OFF = 38731776;
    const size_t F_OFF = 43573248;
    const size_t G_OFF = 48490496;
    const size_t H_OFF = 48515584;
    const size_t I_OFF = 48524416;

    float*  h        = ws + A_OFF;
    ushort* v_bfT    = (ushort*)(ws + A_OFF);
    ushort* mlp_bf   = (ushort*)(ws + A_OFF);
    ushort* h_bf     = (ushort*)(ws + C_OFF);
    float*  qk       = ws + B_OFF;
    float*  xp       = ws + B_OFF;
    ushort* xattp_bf = (ushort*)(ws + B_OFF + 6832128);
    ushort* h2_bf    = (ushort*)(ws + B_OFF + 10248192);
    ushort* v_bf     = (ushort*)(ws + D_OFF);
    ushort* xatt_bf  = (ushort*)(ws + E_OFF);
    double* patch64  = (double*)(ws + F_OFF);
    ushort* fc1_t    = (ushort*)(ws + F_OFF);
    ushort* fc2_t    = (ushort*)(ws + F_OFF + 1179648);
    double* cls64    = (double*)(ws + G_OFF);
    int*    tok      = (int*)(ws + H_OFF);
    ushort* wv_t     = (ushort*)(ws + I_OFF);
    ushort* proj_t   = (ushort*)(ws + I_OFF + 294912);

    float* out_x   = (float*)d_out;            // 6,832,128
    float* out_idx = out_x + 6832128;          // 8,832
    float* out_msk = out_idx + 8832;           // 1,236,544
    float* out_cls = out_msk + 1236544;        // 12,544

    const int ROWS1 = BB * NN;        // 12608
    const int ROWS2 = BB * NOUT_TOK;  // 8896

    // 1. LN1: h fp32 (QK exact path) + h_bf (V MFMA path)
    ln_kernel<<<ROWS1, 256, 0, stream>>>(x, n1g, n1b, h, h_bf);
    // 2. weight transposes (bf16): Wv (qkv_w cols 1536..2303), proj
    transw_kernel<<<dim3(24, 24), 256, 0, stream>>>(qkv_w + 1536, 2304, wv_t, 768);
    transw_kernel<<<dim3(24, 24), 256, 0, stream>>>(proj_w, 768, proj_t, 768);
    // 3. Q,K GEMM fp32 + fp64 chunks (exact path), M padded to 12672,
    //    128x128 tile / 8x8 microtile (pad rows write into v_bf, which is
    //    fully overwritten by step 4 before any read)
    gemm_qk_kernel<<<dim3(1536 / 128, 12672 / 128), 256, 0, stream>>>(
        h, qkv_w, qkv_b, qk, 768, 2304, 1536);
    // 4. V GEMM (bf16 MFMA, 128x128) -> v_bf, M padded to 12672
    mfma_gemm<0, true><<<dim3(768 / 128, 12672 / 128), 512, 0, stream>>>(
        h_bf, wv_t, qkv_b + 1536, nullptr, v_bf, ROWS1, 768, 768);
    // 4b. V transpose -> v_bfT [b][h][d][224] (h region now dead)
    transv_kernel<<<dim3(7, HH, BB), 256, 0, stream>>>(v_bf, v_bfT);
    // 5. fused attention (exact softmax chain + MFMA PV), 7 tiles of 32 rows
    attn_kernel<<<dim3(7, BB), 512, 0, stream>>>(qk, v_bfT, amask, xatt_bf, cls64, patch64);
    // 6. top-k token selection (+ cls fp32 output)
    topk_kernel<<<BB, 256, 0, stream>>>(cls64, tok, out_idx, out_cls);
    // 7. gather rows (x -> xp residual, xatt_bf -> xattp_bf)
    gather_kernel<<<dim3(NOUT_TOK, BB), 256, 0, stream>>>(x, xatt_bf, tok, xp, xattp_bf);
    // 8. proj (bf16 MFMA, 128x128) + residual, in-place into xp; M pad 8960
    mfma_gemm<1, false><<<dim3(768 / 128, 8960 / 128), 512, 0, stream>>>(
        xattp_bf, proj_t, proj_b, xp, xp, ROWS2, 768, 768);
    // 9. attention mask (fp64, gathers patch64 directly)
    mask_kernel<<<dim3(NOUT_TOK, BB), 256, 0, stream>>>(patch64, tok, out_msk);
    // 10. fc weight transposes (into patch64's region, now dead)
    transw_kernel<<<dim3(96, 24), 256, 0, stream>>>(fc1_w, 3072, fc1_t, 768);
    transw_kernel<<<dim3(24, 96), 256, 0, stream>>>(fc2_w, 768, fc2_t, 3072);
    // 11. LN2 -> h2_bf
    ln_kernel<<<ROWS2, 256, 0, stream>>>(xp, n2g, n2b, nullptr, h2_bf);
    // 12. fc1 + gelu (bf16 MFMA, 128x128) -> mlp_bf; M pad 8960
    mfma_gemm<2, true><<<dim3(3072 / 128, 8960 / 128), 512, 0, stream>>>(
        h2_bf, fc1_t, fc1_b, nullptr, mlp_bf, ROWS2, 768, 3072);
    // 13. fc2 (bf16 MFMA, 128x128) + bias + residual -> out x; M pad 8960
    mfma_gemm<1, false><<<dim3(768 / 128, 8960 / 128), 512, 0, stream>>>(
        mlp_bf, fc2_t, fc2_b, xp, out_x, ROWS2, 3072, 768);
}

// Round 16
// 1185.477 us; speedup vs baseline: 1.1030x; 1.1030x over previous
//
#include <hip/hip_runtime.h>
#include <hip/hip_bf16.h>
#include <math.h>

// Problem constants
#define BB 64
#define NN 197
#define CC 768
#define HH 12
#define MLPD 3072
#define NKEEP 138
#define NKEEPA 97
#define NPATCH 196
#define NOUT_TOK 139
#define STILE 32

typedef __attribute__((ext_vector_type(8))) short bf16x8;
typedef __attribute__((ext_vector_type(4))) float f32x4;

static __device__ inline ushort f2bf(float f) {
    __hip_bfloat16 h = __float2bfloat16(f);
    return *(ushort*)&h;
}
static __device__ inline float bf2f(ushort u) {
    __hip_bfloat16 h;
    *(ushort*)&h = u;
    return __bfloat162float(h);
}

// ---------------------------------------------------------------------------
// fp64 exp (poly), rel err ~1e-14; for softmax args (x <= 0, moderate)
// ---------------------------------------------------------------------------
__device__ inline double exp64(double x) {
    const double L2E    = 1.4426950408889634074;
    const double LN2_HI = 6.93147180369123816490e-01;
    const double LN2_LO = 1.90821492927058770002e-10;
    double nf = rint(x * L2E);
    double r  = fma(-nf, LN2_HI, x);
    r = fma(-nf, LN2_LO, r);
    double p = 1.0 / 3628800.0;
    p = fma(p, r, 1.0 / 362880.0);
    p = fma(p, r, 1.0 / 40320.0);
    p = fma(p, r, 1.0 / 5040.0);
    p = fma(p, r, 1.0 / 720.0);
    p = fma(p, r, 1.0 / 120.0);
    p = fma(p, r, 1.0 / 24.0);
    p = fma(p, r, 1.0 / 6.0);
    p = fma(p, r, 0.5);
    p = fma(p, r, 1.0);
    p = fma(p, r, 1.0);
    long long bits = ((long long)(1023 + (int)nf)) << 52;
    return p * __longlong_as_double(bits);
}

__device__ inline double wave_max64(double v) {
#pragma unroll
    for (int o = 32; o; o >>= 1) v = fmax(v, __shfl_xor(v, o));
    return v;
}
__device__ inline double wave_sum64(double v) {
#pragma unroll
    for (int o = 32; o; o >>= 1) v += __shfl_xor(v, o);
    return v;
}

// gathered source row for compacted row index (clamped for grid padding)
__device__ inline int gat_src(int row, const int* __restrict__ tok) {
    if (row > BB * NOUT_TOK - 1) row = BB * NOUT_TOK - 1;
    const int b = row / NOUT_TOK, i = row % NOUT_TOK;
    return b * NN + ((i == 0) ? 0 : (1 + tok[b * NKEEP + i - 1]));
}

// ---------------------------------------------------------------------------
// LayerNorm, fp64 wave-shuffle reductions; elements cached in registers.
// ---------------------------------------------------------------------------
__global__ __launch_bounds__(256) void ln_kernel(const float* __restrict__ in,
                                                 const float* __restrict__ g,
                                                 const float* __restrict__ b,
                                                 float* __restrict__ out32,
                                                 ushort* __restrict__ out16) {
    const int row = blockIdx.x;
    const int t = threadIdx.x;
    const int lane = t & 63, w = t >> 6;
    const float* xr = in + (size_t)row * CC;
    __shared__ double wred[4];

    const float v0 = xr[t], v1 = xr[t + 256], v2 = xr[t + 512];
    double s = (double)v0 + (double)v1 + (double)v2;
    s = wave_sum64(s);
    if (lane == 0) wred[w] = s;
    __syncthreads();
    const double mu = (wred[0] + wred[1] + wred[2] + wred[3]) * (1.0 / CC);

    const double d0 = (double)v0 - mu, d1 = (double)v1 - mu, d2 = (double)v2 - mu;
    double vs = d0 * d0 + d1 * d1 + d2 * d2;
    vs = wave_sum64(vs);
    __syncthreads();
    if (lane == 0) wred[w] = vs;
    __syncthreads();
    const double inv = 1.0 / sqrt((wred[0] + wred[1] + wred[2] + wred[3]) * (1.0 / CC) + 1e-5);

    const int cs[3] = {t, t + 256, t + 512};
    const double dv[3] = {d0, d1, d2};
#pragma unroll
    for (int i = 0; i < 3; i++) {
        float v = (float)(dv[i] * inv * (double)g[cs[i]] + (double)b[cs[i]]);
        if (out32) out32[(size_t)row * CC + cs[i]] = v;
        if (out16) out16[(size_t)row * CC + cs[i]] = f2bf(v);
    }
}

// ---------------------------------------------------------------------------
// Exact-path fp32 GEMM, fp64 merge every 16 k (validated round-13 version).
// BM=128, BN=64, BK=32, 256 threads, 8x4 microtile, reg-prefetch staging.
// NOTE: local optimum at ~503 us — dbuf (r7), f32x2 pack (r14), 8x8 tile
// (r15) all neutral or regressed (VGPR>128 halves occupancy; r15 conflicts).
// ---------------------------------------------------------------------------
__global__ __launch_bounds__(256) void gemm_qk_kernel(const float* __restrict__ A,
                                                      const float* __restrict__ Bw,
                                                      const float* __restrict__ bias,
                                                      float* __restrict__ C,
                                                      int K, int ldb, int ldc) {
    __shared__ float As[32][132];   // [k][row]
    __shared__ float Bs[32][68];    // [k][col]
    const int tid = threadIdx.x;
    const int tx = tid & 15;
    const int ty = tid >> 4;
    const int m0 = blockIdx.y * 128;
    const int n0 = blockIdx.x * 64;

    const int a_k = tid & 31, a_g = tid >> 5;   // A loader: k, row-group(16)
    const int b_n = tid & 63, b_kg = tid >> 6;  // B loader: col, k-group(8)

    float acc[8][4];
    double dacc[8][4];
#pragma unroll
    for (int i = 0; i < 8; i++)
#pragma unroll
        for (int j = 0; j < 4; j++) { acc[i][j] = 0.f; dacc[i][j] = 0.0; }

    float a_reg[16], b_reg[8];
#pragma unroll
    for (int i = 0; i < 16; i++)
        a_reg[i] = A[(size_t)(m0 + a_g * 16 + i) * 768 + a_k];
#pragma unroll
    for (int i = 0; i < 8; i++)
        b_reg[i] = Bw[(size_t)(b_kg * 8 + i) * ldb + n0 + b_n];

    for (int k0 = 0; k0 < K; k0 += 32) {
        __syncthreads();
#pragma unroll
        for (int i = 0; i < 4; i++)
            *(float4*)&As[a_k][a_g * 16 + i * 4] =
                make_float4(a_reg[i * 4], a_reg[i * 4 + 1], a_reg[i * 4 + 2], a_reg[i * 4 + 3]);
#pragma unroll
        for (int i = 0; i < 8; i++) Bs[b_kg * 8 + i][b_n] = b_reg[i];
        __syncthreads();
        if (k0 + 32 < K) {
#pragma unroll
            for (int i = 0; i < 16; i++)
                a_reg[i] = A[(size_t)(m0 + a_g * 16 + i) * 768 + k0 + 32 + a_k];
#pragma unroll
            for (int i = 0; i < 8; i++)
                b_reg[i] = Bw[(size_t)(k0 + 32 + b_kg * 8 + i) * ldb + n0 + b_n];
        }
#pragma unroll
        for (int k = 0; k < 32; k++) {
            float4 a0 = *(const float4*)&As[k][ty * 8];
            float4 a1 = *(const float4*)&As[k][ty * 8 + 4];
            float4 bv = *(const float4*)&Bs[k][tx * 4];
            float a_[8] = {a0.x, a0.y, a0.z, a0.w, a1.x, a1.y, a1.z, a1.w};
            float b_[4] = {bv.x, bv.y, bv.z, bv.w};
#pragma unroll
            for (int i = 0; i < 8; i++)
#pragma unroll
                for (int j = 0; j < 4; j++)
                    acc[i][j] = fmaf(a_[i], b_[j], acc[i][j]);
            if ((k & 15) == 15) {   // fp64 merge every 16 k
#pragma unroll
                for (int i = 0; i < 8; i++)
#pragma unroll
                    for (int j = 0; j < 4; j++) { dacc[i][j] += (double)acc[i][j]; acc[i][j] = 0.f; }
            }
        }
    }

#pragma unroll
    for (int i = 0; i < 8; i++) {
        const int row = m0 + ty * 8 + i;
#pragma unroll
        for (int j = 0; j < 4; j++) {
            const int col = n0 + tx * 4 + j;
            C[(size_t)row * ldc + col] = (float)(dacc[i][j] + (double)bias[col]);
        }
    }
}

// ---------------------------------------------------------------------------
// bf16 MFMA GEMM: C[M,Nc] = A[M,K](bf16) @ Bt[Nc,K](bf16)^T + bias (+res/gelu)
// BM=128, BN=128, BK=32; 512 threads = 8 waves (2x4); wave tile 64x32.
// GATHER: A rows and res rows are indirected through tok (fused row-gather);
// values identical to an explicit gather (same data, same arithmetic).
// ---------------------------------------------------------------------------
template <int MODE, bool OUT_BF16, bool GATHER>
__global__ __launch_bounds__(512) void mfma_gemm(const ushort* __restrict__ A,
                                                 const ushort* __restrict__ Bt,
                                                 const float* __restrict__ bias,
                                                 const float* __restrict__ res,
                                                 void* __restrict__ Cout,
                                                 const int* __restrict__ tok,
                                                 int M, int K, int Nc) {
    __shared__ ushort As[128][40];
    __shared__ ushort Bs[128][40];
    const int tid = threadIdx.x;
    const int w = tid >> 6, lane = tid & 63;
    const int m0 = blockIdx.y * 128, n0 = blockIdx.x * 128;
    const int wr = w >> 2, wc = w & 3;
    const int sr = tid >> 2, sk = (tid & 3) * 8;
    const int lr = lane & 15, lq = lane >> 4;
    const int kq = lq * 8;

    // A staging row (one per thread), optionally gathered
    size_t arow = m0 + sr;
    if (GATHER) arow = gat_src(m0 + sr, tok);

    f32x4 acc[4][2];
#pragma unroll
    for (int i = 0; i < 4; i++)
#pragma unroll
        for (int j = 0; j < 2; j++) acc[i][j] = (f32x4){0.f, 0.f, 0.f, 0.f};

    bf16x8 a_pre = *(const bf16x8*)&A[arow * K + sk];
    bf16x8 b_pre = *(const bf16x8*)&Bt[(size_t)(n0 + sr) * K + sk];

    for (int k0 = 0; k0 < K; k0 += 32) {
        __syncthreads();
        *(bf16x8*)&As[sr][sk] = a_pre;
        *(bf16x8*)&Bs[sr][sk] = b_pre;
        __syncthreads();
        if (k0 + 32 < K) {
            a_pre = *(const bf16x8*)&A[arow * K + k0 + 32 + sk];
            b_pre = *(const bf16x8*)&Bt[(size_t)(n0 + sr) * K + k0 + 32 + sk];
        }

        bf16x8 af[4], bfr[2];
#pragma unroll
        for (int i = 0; i < 4; i++) af[i] = *(const bf16x8*)&As[wr * 64 + i * 16 + lr][kq];
#pragma unroll
        for (int j = 0; j < 2; j++) bfr[j] = *(const bf16x8*)&Bs[wc * 32 + j * 16 + lr][kq];
#pragma unroll
        for (int i = 0; i < 4; i++)
#pragma unroll
            for (int j = 0; j < 2; j++)
                acc[i][j] = __builtin_amdgcn_mfma_f32_16x16x32_bf16(af[i], bfr[j], acc[i][j], 0, 0, 0);
    }

#pragma unroll
    for (int i = 0; i < 4; i++)
#pragma unroll
        for (int r = 0; r < 4; r++) {
            const int row = m0 + wr * 64 + i * 16 + lq * 4 + r;
            if (row >= M) continue;
            size_t rrow = row;
            if (GATHER && MODE == 1) rrow = gat_src(row, tok);
#pragma unroll
            for (int j = 0; j < 2; j++) {
#pragma unroll
                for (int e = 0; e < 4; e++) {
                    const int col = n0 + wc * 32 + j * 16 + lr;
                    (void)e;
                }
            }
#pragma unroll
            for (int j = 0; j < 2; j++) {
                const int col = n0 + wc * 32 + j * 16 + lr;
                float v = acc[i][j][r] + bias[col];
                if (MODE == 1) v += res[rrow * Nc + col];
                if (MODE == 2) v = 0.5f * v * (1.0f + erff(v * 0.70710678118654752f));
                if (OUT_BF16) ((ushort*)Cout)[(size_t)row * Nc + col] = f2bf(v);
                else ((float*)Cout)[(size_t)row * Nc + col] = v;
            }
        }
}

// ---------------------------------------------------------------------------
// Weight transpose + bf16 convert: Wt[n][k] = bf16(W[k*ldw + n])
// ---------------------------------------------------------------------------
__global__ __launch_bounds__(256) void transw_kernel(const float* __restrict__ W, int ldw,
                                                     ushort* __restrict__ Wt, int K) {
    __shared__ float tile[32][33];
    const int n0 = blockIdx.x * 32, k0 = blockIdx.y * 32;
    const int tx = threadIdx.x & 31, ty = threadIdx.x >> 5;
#pragma unroll
    for (int r = 0; r < 32; r += 8)
        tile[ty + r][tx] = W[(size_t)(k0 + ty + r) * ldw + n0 + tx];
    __syncthreads();
#pragma unroll
    for (int r = 0; r < 32; r += 8)
        Wt[(size_t)(n0 + ty + r) * K + k0 + tx] = f2bf(tile[tx][ty + r]);
}

// ---------------------------------------------------------------------------
// V transpose to [b][h][d][224] bf16 (pads m in [197,224) zeroed).
// ---------------------------------------------------------------------------
__global__ __launch_bounds__(256) void transv_kernel(const ushort* __restrict__ vbf,
                                                     ushort* __restrict__ vbfT) {
    __shared__ ushort tile[32][72];
    const int mt = blockIdx.x, hh = blockIdx.y, b = blockIdx.z;
    const int t = threadIdx.x;
    {
        const int mm = t >> 3, dq = (t & 7) * 8;
        const int m = mt * 32 + mm;
        bf16x8 v = (bf16x8){0, 0, 0, 0, 0, 0, 0, 0};
        if (m < NN)
            v = *(const bf16x8*)&vbf[((size_t)(b * NN + m)) * CC + hh * 64 + dq];
        *(bf16x8*)&tile[mm][dq] = v;
    }
    __syncthreads();
    {
        const int d = t >> 2, mq = (t & 3) * 8;
        ushort tmp[8];
#pragma unroll
        for (int j = 0; j < 8; j++) tmp[j] = tile[mq + j][d];
        *(bf16x8*)&vbfT[(((size_t)(b * HH + hh)) * 64 + d) * 224 + mt * 32 + mq] =
            *(bf16x8*)tmp;
    }
}

// ---------------------------------------------------------------------------
// Fused attention: exact scores (fp32 fma + chunk-8 fp64) + fp64 softmax +
// MFMA PV. grid (7 tiles of 32 rows, B), 512 threads (8 waves).
// NOTE: scores merge MUST stay chunk-8 — chunk-16 spills fp64 accumulators
// to scratch (round 9: 14.8 GB HBM traffic, 25x slowdown).
// ---------------------------------------------------------------------------
#define KSTR 68
#define PSTR 232
__global__ __launch_bounds__(512) void attn_kernel(const float* __restrict__ qk,
                                                   const ushort* __restrict__ vbfT,
                                                   const float* __restrict__ amask,
                                                   ushort* __restrict__ xatt_bf,
                                                   double* __restrict__ cls64,
                                                   double* __restrict__ patch64) {
    const int tile = blockIdx.x;
    const int b = blockIdx.y;
    const int row0 = tile * STILE;
    const int nrows = min(STILE, NN - row0);
    const int t = threadIdx.x;
    const int w = t >> 6, lane = t & 63;

    __shared__ __align__(16) char pool[61776];
    float*  Kf = (float*)pool;               // [197][68]
    float*  Qf = (float*)(pool + 53584);     // [32][64]
    ushort* Vt = (ushort*)pool;              // [64][232]
    ushort* Pb = (ushort*)(pool + 32768);    // [32][232]

    int mcol[4], mc[4];
    bool mok[4];
#pragma unroll
    for (int c = 0; c < 4; c++) {
        mcol[c] = lane + 64 * c;
        mok[c] = mcol[c] < NN;
        mc[c] = mok[c] ? mcol[c] : 0;
    }
    int rloc[4];
    bool rok[4];
#pragma unroll
    for (int rr = 0; rr < 4; rr++) {
        rloc[rr] = w + 8 * rr;
        rok[rr] = rloc[rr] < nrows;
    }

    float mv[4][4];
#pragma unroll
    for (int rr = 0; rr < 4; rr++)
#pragma unroll
        for (int c = 0; c < 4; c++)
            mv[rr][c] = (rok[rr] && mok[c])
                ? amask[((size_t)(b * NN + row0 + rloc[rr])) * NN + mcol[c]] : 0.f;

    const int rt = w >> 2, ct = w & 3;
    const int lr = lane & 15, lq = lane >> 4;

    double hacc[4][4] = {};

    for (int h = 0; h < HH; ++h) {
        __syncthreads();
        for (int idx = t; idx < NN * 16; idx += 512) {
            int m = idx >> 4, dq = (idx & 15) * 4;
            *(float4*)&Kf[m * KSTR + dq] =
                *(const float4*)&qk[((size_t)(b * NN + m)) * 1536 + 768 + h * 64 + dq];
        }
        for (int idx = t; idx < nrows * 64; idx += 512) {
            int r = idx >> 6, d = idx & 63;
            Qf[r * 64 + d] = qk[((size_t)(b * NN + row0 + r)) * 1536 + h * 64 + d];
        }
        __syncthreads();

        double s[4][4] = {};
        {
            float facc[4][4] = {};
            for (int d0 = 0; d0 < 64; d0 += 4) {
                float4 qv[4];
#pragma unroll
                for (int rr = 0; rr < 4; rr++)
                    qv[rr] = rok[rr] ? *(const float4*)&Qf[rloc[rr] * 64 + d0]
                                     : make_float4(0.f, 0.f, 0.f, 0.f);
#pragma unroll
                for (int c = 0; c < 4; c++) {
                    float4 kv = *(const float4*)&Kf[mc[c] * KSTR + d0];
#pragma unroll
                    for (int rr = 0; rr < 4; rr++) {
                        facc[rr][c] = fmaf(qv[rr].x, kv.x,
                                      fmaf(qv[rr].y, kv.y,
                                      fmaf(qv[rr].z, kv.z,
                                      fmaf(qv[rr].w, kv.w, facc[rr][c]))));
                    }
                }
                if ((d0 & 4) == 4) {   // chunk-8 fp64 merge (do not widen!)
#pragma unroll
                    for (int rr = 0; rr < 4; rr++)
#pragma unroll
                        for (int c = 0; c < 4; c++) {
                            s[rr][c] += (double)facc[rr][c];
                            facc[rr][c] = 0.f;
                        }
                }
            }
        }
        __syncthreads();

#pragma unroll
        for (int rr = 0; rr < 4; rr++) {
            if (!rok[rr]) continue;  // wave-uniform
            double sc[4];
#pragma unroll
            for (int c = 0; c < 4; c++)
                sc[c] = mok[c] ? s[rr][c] * 0.125 : -1.0e300;
            double mx = fmax(fmax(sc[0], sc[1]), fmax(sc[2], sc[3]));
            mx = wave_max64(mx);
            double e[4];
#pragma unroll
            for (int c = 0; c < 4; c++)
                e[c] = mok[c] ? exp64(sc[c] - mx) * (double)mv[rr][c] : 0.0;
            double S = wave_sum64(e[0] + e[1] + e[2] + e[3]);
            double inv = 1.0 / (S + 1e-6);
            const double epsn = 1e-6 / 197.0;
#pragma unroll
            for (int c = 0; c < 4; c++) {
                if (!mok[c]) continue;
                double pr = (e[c] + epsn) * inv;
                Pb[rloc[rr] * PSTR + mcol[c]] = f2bf((float)pr);
                hacc[rr][c] += pr;
            }
        }
        // zero P pads (Pb aliases Kf region -> rewritten every head)
        for (int idx = t; idx < 32 * 27; idx += 512) {
            int r = idx / 27, m = 197 + idx % 27;
            Pb[r * PSTR + m] = 0;
        }
        for (int idx = t; idx < (STILE - nrows) * 197; idx += 512) {
            int r = nrows + idx / 197, m = idx % 197;
            Pb[r * PSTR + m] = 0;
        }
        // stage V from pre-transposed global: contiguous bf16x8, no conflicts
        {
            const ushort* vsrc = vbfT + ((size_t)(b * HH + h)) * 64 * 224;
            for (int idx = t; idx < 64 * 28; idx += 512) {
                int d = idx / 28, mb = (idx % 28) * 8;
                *(bf16x8*)&Vt[d * PSTR + mb] = *(const bf16x8*)&vsrc[d * 224 + mb];
            }
        }
        __syncthreads();

        f32x4 acc = (f32x4){0.f, 0.f, 0.f, 0.f};
#pragma unroll
        for (int k0 = 0; k0 < 224; k0 += 32) {
            bf16x8 pa = *(const bf16x8*)&Pb[(rt * 16 + lr) * PSTR + k0 + lq * 8];
            bf16x8 vb = *(const bf16x8*)&Vt[(ct * 16 + lr) * PSTR + k0 + lq * 8];
            acc = __builtin_amdgcn_mfma_f32_16x16x32_bf16(pa, vb, acc, 0, 0, 0);
        }
#pragma unroll
        for (int rg = 0; rg < 4; rg++) {
            const int row = rt * 16 + lq * 4 + rg;
            if (row < nrows)
                xatt_bf[((size_t)(b * NN + row0 + row)) * CC + h * 64 + ct * 16 + lr] =
                    f2bf(acc[rg]);
        }
    }

#pragma unroll
    for (int rr = 0; rr < 4; rr++) {
        if (!rok[rr]) continue;
        const int grow = row0 + rloc[rr];
#pragma unroll
        for (int c = 0; c < 4; c++) {
            if (!mok[c] || mcol[c] < 1) continue;
            double v = hacc[rr][c] * (1.0 / 12.0);
            if (grow == 0)
                cls64[(size_t)b * NPATCH + mcol[c] - 1] = v;
            else
                patch64[((size_t)b * NPATCH + grow - 1) * NPATCH + (mcol[c] - 1)] = v;
        }
    }
}

// ---------------------------------------------------------------------------
// Top-k (stable, descending) of cls64 + fp32 cls output.
// ---------------------------------------------------------------------------
__global__ __launch_bounds__(256) void topk_kernel(const double* __restrict__ cls,
                                                   int* __restrict__ tok,
                                                   float* __restrict__ tok_f,
                                                   float* __restrict__ out_cls) {
    const int b = blockIdx.x;
    const int t = threadIdx.x;
    __shared__ double v[NPATCH];
    if (t < NPATCH) {
        v[t] = cls[(size_t)b * NPATCH + t];
        out_cls[(size_t)b * NPATCH + t] = (float)v[t];
    }
    __syncthreads();
    if (t < NPATCH) {
        const double mvv = v[t];
        int cnt = 0;
        for (int i = 0; i < NPATCH; ++i) {
            double vi = v[i];
            cnt += (vi > mvv) || (vi == mvv && i < t);
        }
        if (cnt < NKEEP) {
            tok[b * NKEEP + cnt] = t;
            tok_f[b * NKEEP + cnt] = (float)t;
        }
    }
}

// mask from patch64 gathered on the fly
__global__ __launch_bounds__(256) void mask_kernel(const double* __restrict__ patch,
                                                   const int* __restrict__ tok,
                                                   float* __restrict__ omask) {
    const int i = blockIdx.x;
    const int b = blockIdx.y;
    const int t = threadIdx.x;
    float* orow = omask + ((size_t)b * NOUT_TOK + i) * NOUT_TOK;
    if (i == 0) {
        if (t < NOUT_TOK) orow[t] = 1.f;
        return;
    }
    __shared__ int tj[NKEEP];
    __shared__ double pr[NKEEP];
    if (t < NKEEP) tj[t] = tok[b * NKEEP + t];
    __syncthreads();
    const int ti = tj[i - 1];
    if (t < NKEEP) pr[t] = patch[((size_t)b * NPATCH + ti) * NPATCH + tj[t]];
    __syncthreads();
    if (t == 255) orow[0] = 1.f;
    if (t < NKEEP) {
        const double val = pr[t];
        int cnt = 0;
        for (int l = 0; l < NKEEP; ++l) cnt += (pr[l] > val);
        orow[1 + t] = (cnt < NKEEPA) ? 1.f : 0.f;
    }
}

// ---------------------------------------------------------------------------
extern "C" void kernel_launch(void* const* d_in, const int* in_sizes, int n_in,
                              void* d_out, int out_size, void* d_ws, size_t ws_size,
                              hipStream_t stream) {
    const float* x      = (const float*)d_in[0];
    const float* amask  = (const float*)d_in[1];
    const float* n1g    = (const float*)d_in[2];
    const float* n1b    = (const float*)d_in[3];
    const float* qkv_w  = (const float*)d_in[4];
    const float* qkv_b  = (const float*)d_in[5];
    const float* proj_w = (const float*)d_in[6];
    const float* proj_b = (const float*)d_in[7];
    const float* n2g    = (const float*)d_in[8];
    const float* n2b    = (const float*)d_in[9];
    const float* fc1_w  = (const float*)d_in[10];
    const float* fc1_b  = (const float*)d_in[11];
    const float* fc2_w  = (const float*)d_in[12];
    const float* fc2_b  = (const float*)d_in[13];

    float* ws = (float*)d_ws;
    // Workspace layout (float offsets). Total 49,114,240 f = 196.5 MB.
    const size_t A_OFF = 0;
    const size_t C_OFF = 9682944;
    const size_t B_OFF = 14524416;
    const size_t D_OFF = 33890304;
    const size_t E_OFF = 38731776;
    const size_t F_OFF = 43573248;
    const size_t G_OFF = 48490496;
    const size_t H_OFF = 48515584;
    const size_t I_OFF = 48524416;

    float*  h        = ws + A_OFF;
    ushort* v_bfT    = (ushort*)(ws + A_OFF);
    ushort* mlp_bf   = (ushort*)(ws + A_OFF);
    ushort* h_bf     = (ushort*)(ws + C_OFF);
    float*  qk       = ws + B_OFF;
    float*  xp       = ws + B_OFF;
    ushort* h2_bf    = (ushort*)(ws + B_OFF + 10248192);
    ushort* v_bf     = (ushort*)(ws + D_OFF);
    ushort* xatt_bf  = (ushort*)(ws + E_OFF);
    double* patch64  = (double*)(ws + F_OFF);
    ushort* fc1_t    = (ushort*)(ws + F_OFF);
    ushort* fc2_t    = (ushort*)(ws + F_OFF + 1179648);
    double* cls64    = (double*)(ws + G_OFF);
    int*    tok      = (int*)(ws + H_OFF);
    ushort* wv_t     = (ushort*)(ws + I_OFF);
    ushort* proj_t   = (ushort*)(ws + I_OFF + 294912);

    float* out_x   = (float*)d_out;            // 6,832,128
    float* out_idx = out_x + 6832128;          // 8,832
    float* out_msk = out_idx + 8832;           // 1,236,544
    float* out_cls = out_msk + 1236544;        // 12,544

    const int ROWS1 = BB * NN;        // 12608
    const int ROWS2 = BB * NOUT_TOK;  // 8896

    // 1. LN1: h fp32 (QK exact path) + h_bf (V MFMA path)
    ln_kernel<<<ROWS1, 256, 0, stream>>>(x, n1g, n1b, h, h_bf);
    // 2. weight transposes (bf16): Wv (qkv_w cols 1536..2303), proj
    transw_kernel<<<dim3(24, 24), 256, 0, stream>>>(qkv_w + 1536, 2304, wv_t, 768);
    transw_kernel<<<dim3(24, 24), 256, 0, stream>>>(proj_w, 768, proj_t, 768);
    // 3. Q,K GEMM fp32 + fp64 chunks (exact path), M padded to 12672, BK=32
    gemm_qk_kernel<<<dim3(1536 / 64, 12672 / 128), 256, 0, stream>>>(
        h, qkv_w, qkv_b, qk, 768, 2304, 1536);
    // 4. V GEMM (bf16 MFMA, 128x128) -> v_bf, M padded to 12672
    mfma_gemm<0, true, false><<<dim3(768 / 128, 12672 / 128), 512, 0, stream>>>(
        h_bf, wv_t, qkv_b + 1536, nullptr, v_bf, nullptr, ROWS1, 768, 768);
    // 4b. V transpose -> v_bfT [b][h][d][224] (h region now dead)
    transv_kernel<<<dim3(7, HH, BB), 256, 0, stream>>>(v_bf, v_bfT);
    // 5. fused attention (exact softmax chain + MFMA PV), 7 tiles of 32 rows
    attn_kernel<<<dim3(7, BB), 512, 0, stream>>>(qk, v_bfT, amask, xatt_bf, cls64, patch64);
    // 6. top-k token selection (+ cls fp32 output)
    topk_kernel<<<BB, 256, 0, stream>>>(cls64, tok, out_idx, out_cls);
    // 7. proj (bf16 MFMA, fused row-gather via tok) + residual (x, gathered)
    //    -> xp; M pad 8960 (qk region dead after attn)
    mfma_gemm<1, false, true><<<dim3(768 / 128, 8960 / 128), 512, 0, stream>>>(
        xatt_bf, proj_t, proj_b, x, xp, tok, ROWS2, 768, 768);
    // 8. attention mask (fp64, gathers patch64 directly)
    mask_kernel<<<dim3(NOUT_TOK, BB), 256, 0, stream>>>(patch64, tok, out_msk);
    // 9. fc weight transposes (into patch64's region, now dead)
    transw_kernel<<<dim3(96, 24), 256, 0, stream>>>(fc1_w, 3072, fc1_t, 768);
    transw_kernel<<<dim3(24, 96), 256, 0, stream>>>(fc2_w, 768, fc2_t, 3072);
    // 10. LN2 -> h2_bf
    ln_kernel<<<ROWS2, 256, 0, stream>>>(xp, n2g, n2b, nullptr, h2_bf);
    // 11. fc1 + gelu (bf16 MFMA, 128x128) -> mlp_bf; M pad 8960
    mfma_gemm<2, true, false><<<dim3(3072 / 128, 8960 / 128), 512, 0, stream>>>(
        h2_bf, fc1_t, fc1_b, nullptr, mlp_bf, nullptr, ROWS2, 768, 3072);
    // 12. fc2 (bf16 MFMA, 128x128) + bias + residual -> out x; M pad 8960
    mfma_gemm<1, false, false><<<dim3(768 / 128, 8960 / 128), 512, 0, stream>>>(
        mlp_bf, fc2_t, fc2_b, xp, out_x, nullptr, ROWS2, 3072, 768);
}